// Round 3
// baseline (175.561 us; speedup 1.0000x reference)
//
#include <hip/hip_runtime.h>

typedef unsigned short u16;
typedef __attribute__((ext_vector_type(8))) short sh8;           // 8 bf16 (4 VGPR)
typedef __attribute__((ext_vector_type(8))) unsigned short us8;
typedef __attribute__((ext_vector_type(4))) float f4;

__device__ __forceinline__ float bf2f(u16 u) {
  union { unsigned u; float f; } v; v.u = ((unsigned)u) << 16; return v.f;
}
__device__ __forceinline__ u16 f2bf(float f) {
  union { float f; unsigned u; } v; v.f = f;
  unsigned r = v.u + 0x7fffu + ((v.u >> 16) & 1u);   // RNE, inputs finite
  return (u16)(r >> 16);
}
// async global->LDS, 16B per lane; dest = wave-uniform base + lane*16
__device__ __forceinline__ void gl16(const void* g, void* l) {
  __builtin_amdgcn_global_load_lds(
      (const __attribute__((address_space(1))) unsigned int*)g,
      (__attribute__((address_space(3))) unsigned int*)l, 16, 0, 0);
}

// ---------------- f32 -> bf16, 8 elems/thread ----------------
__global__ __launch_bounds__(256)
void k_cvt_bf16(const float* __restrict__ in, u16* __restrict__ out, int n8) {
  int idx = blockIdx.x * 256 + threadIdx.x;
  if (idx >= n8) return;
  const f4* p = (const f4*)in + (size_t)idx * 2;
  f4 a = p[0], b = p[1];
  us8 o;
  o[0] = f2bf(a[0]); o[1] = f2bf(a[1]); o[2] = f2bf(a[2]); o[3] = f2bf(a[3]);
  o[4] = f2bf(b[0]); o[5] = f2bf(b[1]); o[6] = f2bf(b[2]); o[7] = f2bf(b[3]);
  ((us8*)out)[idx] = o;
}

// ------- weights: concat + transpose to Wt[n][k] bf16, n in [0,6144) -------
__global__ __launch_bounds__(256)
void k_prep_w(const float* __restrict__ Wq, const float* __restrict__ Wl,
              const float* __restrict__ Wc, const float* __restrict__ Wo,
              u16* __restrict__ Wt) {
  __shared__ u16 tile[64][65];
  const int n0 = blockIdx.x * 64;
  const int k0 = blockIdx.y * 64;
  const float* src; int ld, col0;
  if (n0 < 1024)      { src = Wq; ld = 1024; col0 = n0; }
  else if (n0 < 3072) { src = Wl; ld = 2048; col0 = n0 - 1024; }
  else if (n0 < 5120) { src = Wc; ld = 2048; col0 = n0 - 3072; }
  else                { src = Wo; ld = 1024; col0 = n0 - 5120; }
  const int t = threadIdx.x;
  const int r = t >> 2;          // 0..63
  const int c0 = (t & 3) * 16;   // 0,16,32,48
  const float* sp = src + (size_t)(k0 + r) * ld + col0 + c0;
  #pragma unroll
  for (int j = 0; j < 16; j++) tile[r][c0 + j] = f2bf(sp[j]);
  __syncthreads();
  u16* op = Wt + (size_t)(n0 + r) * 1024 + k0 + c0;
  #pragma unroll
  for (int j = 0; j < 16; j++) op[j] = tile[c0 + j][r];
}

// ------- bf16 MFMA GEMM (m97 structure), A[M][K] * Bt[N][K]^T -> C[M][N] -------
// 128x128 tile, BK=64, 256 threads, global_load_lds(16B) into linear LDS.
template<bool OUT_BF16>
__global__ __launch_bounds__(256)
void k_gemm_bt(const u16* __restrict__ A, const u16* __restrict__ Bt,
               void* __restrict__ Cout, int M, int N, int K) {
  __shared__ __align__(16) u16 As[128 * 64];
  __shared__ __align__(16) u16 Bs[128 * 64];
  const int bm0 = blockIdx.y * 128;
  const int bn0 = blockIdx.x * 128;
  const int t = threadIdx.x;
  const int lane = t & 63;
  const int wave = t >> 6;
  const int wr = wave >> 1, wc = wave & 1;
  f4 acc[4][4] = {};
  const int srow = lane >> 3;       // 0..7 row within 8-row chunk
  const int schk = (lane & 7) * 8;  // element col 0..56
  const u16* Abase = A + (size_t)bm0 * K;
  const u16* Bbase = Bt + (size_t)bn0 * K;
  const int fr = lane & 15;
  const int ko = (lane >> 4) * 8;
  for (int kt = 0; kt < K; kt += 64) {
    __syncthreads();   // previous tile's LDS reads complete
    #pragma unroll
    for (int i = 0; i < 4; i++) {
      const int r0 = i * 32 + wave * 8;   // 8 rows per inst per wave
      gl16(Abase + (size_t)(r0 + srow) * K + kt + schk, &As[r0 * 64]);
      gl16(Bbase + (size_t)(r0 + srow) * K + kt + schk, &Bs[r0 * 64]);
    }
    __syncthreads();   // drains vmcnt: tiles resident
    #pragma unroll
    for (int kh = 0; kh < 2; kh++) {
      sh8 af[4], bfv[4];
      const int kofs = kh * 32 + ko;
      #pragma unroll
      for (int mi = 0; mi < 4; mi++)
        af[mi] = *(const sh8*)&As[(wr * 64 + mi * 16 + fr) * 64 + kofs];
      #pragma unroll
      for (int ni = 0; ni < 4; ni++)
        bfv[ni] = *(const sh8*)&Bs[(wc * 64 + ni * 16 + fr) * 64 + kofs];
      #pragma unroll
      for (int mi = 0; mi < 4; mi++)
        #pragma unroll
        for (int ni = 0; ni < 4; ni++)
          acc[mi][ni] = __builtin_amdgcn_mfma_f32_16x16x32_bf16(af[mi], bfv[ni], acc[mi][ni], 0, 0, 0);
    }
  }
  const int rbase = bm0 + wr * 64 + (lane >> 4) * 4;
  const int cbase = bn0 + wc * 64 + fr;
  #pragma unroll
  for (int mi = 0; mi < 4; mi++)
    #pragma unroll
    for (int ni = 0; ni < 4; ni++)
      #pragma unroll
      for (int r = 0; r < 4; r++) {
        const size_t off = (size_t)(rbase + mi * 16 + r) * N + (cbase + ni * 16);
        if constexpr (OUT_BF16) ((u16*)Cout)[off] = f2bf(acc[mi][ni][r]);
        else                    ((float*)Cout)[off] = acc[mi][ni][r];
      }
}

// ---- mean-pool kc/vc -> kpb[bh][128][64] bf16, vpT[bh][64][128] bf16 (pad zeroed) ----
__global__ __launch_bounds__(64)
void k_pool(const u16* __restrict__ proj, u16* __restrict__ kpb, u16* __restrict__ vpT) {
  const int j = blockIdx.x;    // 0..127 (127 = zero pad)
  const int bh = blockIdx.y;   // 0..31
  const int b = bh >> 4, h = bh & 15;
  const int d = threadIdx.x;
  u16 kout = 0, vout = 0;
  if (j < 127) {
    const size_t base = (size_t)(b * 2048 + j * 16) * 5120;
    const size_t kcol = 3072 + h * 64 + d;
    const size_t vcol = 4096 + h * 64 + d;
    float ks = 0.f, vs = 0.f;
    #pragma unroll 4
    for (int r = 0; r < 32; r++) {
      const size_t off = base + (size_t)r * 5120;
      ks += bf2f(proj[off + kcol]);
      vs += bf2f(proj[off + vcol]);
    }
    kout = f2bf(ks * (1.f / 32.f));
    vout = f2bf(vs * (1.f / 32.f));
  }
  kpb[((size_t)bh * 128 + j) * 64 + d] = kout;
  vpT[((size_t)bh * 64 + d) * 128 + j] = vout;
}

// ---- transpose vl: proj cols [2048,3072) -> vlT[bh][64 d][2048 t] bf16 ----
__global__ __launch_bounds__(256)
void k_vt(const u16* __restrict__ proj, u16* __restrict__ vlT) {
  __shared__ u16 tile[64][72];
  const int tt = blockIdx.x;   // 0..31 token tile
  const int bh = blockIdx.y;   // 0..31
  const int b = bh >> 4, h = bh & 15;
  const int t = threadIdx.x;
  const int r = t >> 2;          // 0..63
  const int c0 = (t & 3) * 16;
  const u16* sp = proj + (size_t)(b * 2048 + tt * 64 + r) * 5120 + 2048 + h * 64 + c0;
  us8 v0 = *(const us8*)sp;
  us8 v1 = *(const us8*)(sp + 8);
  #pragma unroll
  for (int jj = 0; jj < 8; jj++) { tile[r][c0 + jj] = v0[jj]; tile[r][c0 + 8 + jj] = v1[jj]; }
  __syncthreads();
  u16* op = vlT + ((size_t)bh * 64 + r) * 2048 + tt * 64 + c0;
  #pragma unroll
  for (int jj = 0; jj < 16; jj++) op[jj] = tile[c0 + jj][r];
}

// ---------------- MFMA attention, LDS-staged K ----------------
// Block = (64-query tile, bh), 4 waves x 16 queries.
// LDS region SB (46080 B), time-multiplexed:
//   phase A: KL[192][72] (u16 off 0) + KC[128][72] (off 13824)  <- global_load_lds
//   phase B: Pl[4][16][200] (off 0) + Pc[4][16][136] (off 12800)
//   phase C: YL[64][72] (off 0) for coalesced y writeback
__global__ __launch_bounds__(256)
void k_attn_mfma(const u16* __restrict__ proj, const u16* __restrict__ kpb,
                 const u16* __restrict__ vpT, const u16* __restrict__ vlT,
                 u16* __restrict__ yb) {
  __shared__ __align__(16) u16 SB[23040];
  const int qt = blockIdx.x;          // 0..31
  const int bh = blockIdx.y;          // 0..31
  const int b = bh >> 4, h = bh & 15;
  const int tid = threadIdx.x;
  const int wave = tid >> 6;
  const int lane = tid & 63;
  const int fr = lane & 15;
  const int g  = lane >> 4;
  const int ko = g * 8;
  const int q0 = qt * 64;
  const int qq = wave * 16 + fr;       // q-in-tile for this lane's column
  const int i_abs = q0 + qq;
  const int kbase = q0 - 128;          // local key j = kbase + kk, kk in [0,192)
  const int kmin = q0 >= 128 ? 0 : 128 - q0;

  const u16* prow = proj + (size_t)(b * 2048) * 5120;
  const sh8 bq0 = *(const sh8*)(prow + (size_t)i_abs * 5120 + h * 64 + ko);
  const sh8 bq1 = *(const sh8*)(prow + (size_t)i_abs * 5120 + h * 64 + 32 + ko);

  // ---- stage KL: 192 rows x 64 (+pad) = 1728 16B chunks, 27 wave-insts ----
  const u16* klb = prow + 1024 + h * 64;
  #pragma unroll
  for (int i = 0; i < 7; i++) {
    const int inst = i * 4 + wave;
    if (inst < 27) {
      const int c = inst * 64 + lane;
      const int row = c / 9;
      const int sl = c - row * 9;
      int rowg = kbase + row; if (rowg < 0) rowg = 0;       // masked rows clamped
      gl16(klb + (size_t)rowg * 5120 + (sl & 7) * 8, &SB[inst * 512]);
    }
  }
  // ---- stage KC: 128 rows x 64 (+pad) = 1152 chunks, 18 wave-insts ----
  const u16* kpr = kpb + (size_t)bh * 128 * 64;
  #pragma unroll
  for (int i = 0; i < 5; i++) {
    const int inst = i * 4 + wave;
    if (inst < 18) {
      const int c = inst * 64 + lane;
      const int row = c / 9;
      const int sl = c - row * 9;
      gl16(kpr + (size_t)row * 64 + (sl & 7) * 8, &SB[13824 + inst * 512]);
    }
  }
  __syncthreads();   // drains vmcnt: K tiles resident

  // ===== local S: 192 keys =====
  f4 st[12];
  #pragma unroll
  for (int f = 0; f < 12; f++) st[f] = f4{0.f, 0.f, 0.f, 0.f};
  #pragma unroll
  for (int kh = 0; kh < 2; kh++) {
    const sh8 bq = kh ? bq1 : bq0;
    #pragma unroll
    for (int f = 0; f < 12; f++) {
      sh8 ak = *(const sh8*)&SB[(f * 16 + fr) * 72 + kh * 32 + ko];
      st[f] = __builtin_amdgcn_mfma_f32_16x16x32_bf16(ak, bq, st[f], 0, 0, 0);
    }
  }
  // ===== comp S: nf*16 pooled keys (wave-uniform skip) =====
  int nf = ((q0 + 63) >> 8) + 1;
  nf = (nf + 1) & ~1;              // even, <= 8
  f4 sc[8];
  #pragma unroll
  for (int f = 0; f < 8; f++) sc[f] = f4{0.f, 0.f, 0.f, 0.f};
  #pragma unroll
  for (int kh = 0; kh < 2; kh++) {
    const sh8 bq = kh ? bq1 : bq0;
    #pragma unroll
    for (int f = 0; f < 8; f++)
      if (f < nf) {
        sh8 ak = *(const sh8*)&SB[13824 + (f * 16 + fr) * 72 + kh * 32 + ko];
        sc[f] = __builtin_amdgcn_mfma_f32_16x16x32_bf16(ak, bq, sc[f], 0, 0, 0);
      }
  }

  // ===== softmax (registers; q is the MFMA column -> 2 shfl_xor reduce) =====
  float m = -1e30f;
  #pragma unroll
  for (int f = 0; f < 12; f++)
    #pragma unroll
    for (int r = 0; r < 4; r++) {
      const int kk = f * 16 + g * 4 + r;
      const bool ok = (kk > qq) && (kk <= qq + 128) && (kk >= kmin);
      const float v = ok ? st[f][r] * 0.125f : -1e30f;
      st[f][r] = v; m = fmaxf(m, v);
    }
  m = fmaxf(m, __shfl_xor(m, 16));
  m = fmaxf(m, __shfl_xor(m, 32));
  float l = 0.f;
  #pragma unroll
  for (int f = 0; f < 12; f++)
    #pragma unroll
    for (int r = 0; r < 4; r++) {
      const float p = __expf(st[f][r] - m);
      st[f][r] = p; l += p;
    }
  l += __shfl_xor(l, 16);
  l += __shfl_xor(l, 32);
  const float inv = 1.f / l;       // l>0: key j=i always in-window

  float m2 = -1e30f;
  #pragma unroll
  for (int f = 0; f < 8; f++)
    #pragma unroll
    for (int r = 0; r < 4; r++) {
      const int jj = f * 16 + g * 4 + r;
      const bool ok = (jj <= 126) && (16 * jj <= i_abs);
      const float v = ok ? sc[f][r] * 0.125f : -1e30f;
      sc[f][r] = v; m2 = fmaxf(m2, v);
    }
  m2 = fmaxf(m2, __shfl_xor(m2, 16));
  m2 = fmaxf(m2, __shfl_xor(m2, 32));
  float l2 = 0.f;
  #pragma unroll
  for (int f = 0; f < 8; f++)
    #pragma unroll
    for (int r = 0; r < 4; r++) {
      const float p = __expf(sc[f][r] - m2);
      sc[f][r] = p; l2 += p;
    }
  l2 += __shfl_xor(l2, 16);
  l2 += __shfl_xor(l2, 32);
  const float inv2 = 1.f / l2;     // l2>0: block 0 allowed for every i

  __syncthreads();   // all waves done reading KL/KC; LDS becomes P
  u16* Pl = &SB[(wave * 16 + fr) * 200];
  u16* Pc = &SB[12800 + (wave * 16 + fr) * 136];
  #pragma unroll
  for (int f = 0; f < 12; f++)
    #pragma unroll
    for (int r = 0; r < 4; r++)
      Pl[f * 16 + g * 4 + r] = f2bf(st[f][r] * inv);
  #pragma unroll
  for (int f = 0; f < 8; f++)
    if (f < nf)
      #pragma unroll
      for (int r = 0; r < 4; r++)
        Pc[f * 16 + g * 4 + r] = f2bf(sc[f][r] * inv2);

  // ===== PV =====
  f4 yacc[4];
  #pragma unroll
  for (int ni = 0; ni < 4; ni++) yacc[ni] = f4{0.f, 0.f, 0.f, 0.f};
  const u16* vt = vlT + (size_t)bh * 64 * 2048;
  #pragma unroll
  for (int ks = 0; ks < 6; ks++) {
    sh8 pa = *(const sh8*)(Pl + ks * 32 + ko);
    int kj = kbase + ks * 32 + ko; if (kj < 0) kj = 0;  // fully-masked span
    #pragma unroll
    for (int ni = 0; ni < 4; ni++) {
      sh8 vb = *(const sh8*)(vt + (size_t)(ni * 16 + fr) * 2048 + kj);
      yacc[ni] = __builtin_amdgcn_mfma_f32_16x16x32_bf16(pa, vb, yacc[ni], 0, 0, 0);
    }
  }
  const u16* vpt = vpT + (size_t)bh * 64 * 128;
  const int nks = nf >> 1;
  #pragma unroll
  for (int ks = 0; ks < 4; ks++)
    if (ks < nks) {
      sh8 pa = *(const sh8*)(Pc + ks * 32 + ko);
      #pragma unroll
      for (int ni = 0; ni < 4; ni++) {
        sh8 vb = *(const sh8*)(vpt + (size_t)(ni * 16 + fr) * 128 + ks * 32 + ko);
        yacc[ni] = __builtin_amdgcn_mfma_f32_16x16x32_bf16(pa, vb, yacc[ni], 0, 0, 0);
      }
    }

  // ===== coalesced y writeback through LDS =====
  __syncthreads();   // P reads done; LDS becomes YL[64][72]
  #pragma unroll
  for (int ni = 0; ni < 4; ni++)
    #pragma unroll
    for (int r = 0; r < 4; r++)
      SB[(wave * 16 + g * 4 + r) * 72 + ni * 16 + fr] = f2bf(yacc[ni][r]);
  __syncthreads();
  {
    const int row = tid >> 2;          // 0..63 query row
    const int c0 = (tid & 3) * 16;     // 16 cols per thread
    u16* gy = yb + (size_t)(b * 2048 + q0 + row) * 1024 + h * 64 + c0;
    *(us8*)gy       = *(const us8*)&SB[row * 72 + c0];
    *(us8*)(gy + 8) = *(const us8*)&SB[row * 72 + c0 + 8];
  }
}

extern "C" void kernel_launch(void* const* d_in, const int* in_sizes, int n_in,
                              void* d_out, int out_size, void* d_ws, size_t ws_size,
                              hipStream_t stream) {
  const float* x  = (const float*)d_in[0];
  const float* Wq = (const float*)d_in[1];
  const float* Wl = (const float*)d_in[2];
  const float* Wc = (const float*)d_in[3];
  const float* Wo = (const float*)d_in[4];
  // dkc/dvc unused: n_def == 0 at T=2048.
  float* out = (float*)d_out;
  char* ws = (char*)d_ws;
  // workspace (72.4 MB): vlT aliases xb (xb dead after gemm1)
  u16* xb   = (u16*)(ws);                       //  8 MB  x bf16 [4096][1024]
  u16* vlT  = (u16*)(ws);                       //  8 MB  vl^T bf16 [32][64][2048] (after gemm1)
  u16* Wt   = (u16*)(ws + 8388608);             // 12 MB  weights^T bf16 [6144][1024]
  u16* proj = (u16*)(ws + 20971520);            // 40 MB  [4096][5120] q|kl|vl|kc|vc
  u16* kpb  = (u16*)(ws + 62914560);            // 512 KB pooled K bf16 [32][128][64]
  u16* vpT  = (u16*)(ws + 63438848);            // 512 KB pooled V^T bf16 [32][64][128]
  u16* yb   = (u16*)(ws + 63963136);            //  8 MB  y bf16 [4096][1024]

  k_cvt_bf16<<<2048, 256, 0, stream>>>(x, xb, 4194304 / 8);
  k_prep_w<<<dim3(96, 16), 256, 0, stream>>>(Wq, Wl, Wc, Wo, Wt);
  k_gemm_bt<true><<<dim3(40, 32), 256, 0, stream>>>(xb, Wt, proj, 4096, 5120, 1024);
  k_pool<<<dim3(128, 32), 64, 0, stream>>>(proj, kpb, vpT);
  k_vt<<<dim3(32, 32), 256, 0, stream>>>(proj, vlT);
  k_attn_mfma<<<dim3(32, 32), 256, 0, stream>>>(proj, kpb, vpT, vlT, yb);
  k_gemm_bt<false><<<dim3(8, 32), 256, 0, stream>>>(yb, Wt + (size_t)5120 * 1024, out, 4096, 1024, 1024);
}

// Round 4
// 173.826 us; speedup vs baseline: 1.0100x; 1.0100x over previous
//
#include <hip/hip_runtime.h>

typedef unsigned short u16;
typedef unsigned int u32;
typedef __attribute__((ext_vector_type(8))) short sh8;           // 8 bf16 (4 VGPR)
typedef __attribute__((ext_vector_type(8))) unsigned short us8;
typedef __attribute__((ext_vector_type(2))) unsigned int ui2;
typedef __attribute__((ext_vector_type(4))) float f4;

__device__ __forceinline__ float bf2f(u16 u) {
  union { unsigned u; float f; } v; v.u = ((unsigned)u) << 16; return v.f;
}
__device__ __forceinline__ u16 f2bf(float f) {
  union { float f; unsigned u; } v; v.f = f;
  unsigned r = v.u + 0x7fffu + ((v.u >> 16) & 1u);   // RNE, inputs finite
  return (u16)(r >> 16);
}
// async global->LDS, 16B per lane; dest = wave-uniform base + lane*16
__device__ __forceinline__ void gl16(const void* g, void* l) {
  __builtin_amdgcn_global_load_lds(
      (const __attribute__((address_space(1))) unsigned int*)g,
      (__attribute__((address_space(3))) unsigned int*)l, 16, 0, 0);
}

// ---------------- f32 -> bf16, 8 elems/thread ----------------
__global__ __launch_bounds__(256)
void k_cvt_bf16(const float* __restrict__ in, u16* __restrict__ out, int n8) {
  int idx = blockIdx.x * 256 + threadIdx.x;
  if (idx >= n8) return;
  const f4* p = (const f4*)in + (size_t)idx * 2;
  f4 a = p[0], b = p[1];
  us8 o;
  o[0] = f2bf(a[0]); o[1] = f2bf(a[1]); o[2] = f2bf(a[2]); o[3] = f2bf(a[3]);
  o[4] = f2bf(b[0]); o[5] = f2bf(b[1]); o[6] = f2bf(b[2]); o[7] = f2bf(b[3]);
  ((us8*)out)[idx] = o;
}

// ------- weights: concat + transpose to Wt[n][k] bf16, n in [0,6144) -------
__global__ __launch_bounds__(256)
void k_prep_w(const float* __restrict__ Wq, const float* __restrict__ Wl,
              const float* __restrict__ Wc, const float* __restrict__ Wo,
              u16* __restrict__ Wt) {
  __shared__ u16 tile[64][65];
  const int n0 = blockIdx.x * 64;
  const int k0 = blockIdx.y * 64;
  const float* src; int ld, col0;
  if (n0 < 1024)      { src = Wq; ld = 1024; col0 = n0; }
  else if (n0 < 3072) { src = Wl; ld = 2048; col0 = n0 - 1024; }
  else if (n0 < 5120) { src = Wc; ld = 2048; col0 = n0 - 3072; }
  else                { src = Wo; ld = 1024; col0 = n0 - 5120; }
  const int t = threadIdx.x;
  const int r = t >> 2;          // 0..63
  const int c0 = (t & 3) * 16;   // 0,16,32,48
  const float* sp = src + (size_t)(k0 + r) * ld + col0 + c0;
  #pragma unroll
  for (int j = 0; j < 16; j++) tile[r][c0 + j] = f2bf(sp[j]);
  __syncthreads();
  u16* op = Wt + (size_t)(n0 + r) * 1024 + k0 + c0;
  #pragma unroll
  for (int j = 0; j < 16; j++) op[j] = tile[c0 + j][r];
}

// ---- bf16 MFMA GEMM (round-2 known-good), A[M][K] * Bt[N][K]^T -> C[M][N] ----
// 128x128 tile, BK=64, 256 threads (4 waves, 2x2), reg-staged + padded LDS.
template<bool OUT_BF16>
__global__ __launch_bounds__(256, 2)
void k_gemm_bt(const u16* __restrict__ A, const u16* __restrict__ Bt,
               void* __restrict__ Cout, int M, int N, int K) {
  constexpr int LDT = 72;
  __shared__ __align__(16) u16 As[128 * LDT];
  __shared__ __align__(16) u16 Bs[128 * LDT];
  const int bm0 = blockIdx.y * 128;
  const int bn0 = blockIdx.x * 128;
  const int t = threadIdx.x;
  const int lane = t & 63;
  const int wave = t >> 6;
  const int wr = wave >> 1, wc = wave & 1;
  f4 acc[4][4] = {};
  const int sr = t >> 1;
  const int sc = (t & 1) * 32;
  const u16* Ap = A + (size_t)(bm0 + sr) * K + sc;
  const u16* Bp = Bt + (size_t)(bn0 + sr) * K + sc;
  u16* AsW = &As[sr * LDT + sc];
  u16* BsW = &Bs[sr * LDT + sc];
  const int fr = lane & 15;
  const int ko = (lane >> 4) * 8;
  for (int kt = 0; kt < K; kt += 64) {
    sh8 a0 = *(const sh8*)(Ap + kt);
    sh8 a1 = *(const sh8*)(Ap + kt + 8);
    sh8 a2 = *(const sh8*)(Ap + kt + 16);
    sh8 a3 = *(const sh8*)(Ap + kt + 24);
    sh8 b0 = *(const sh8*)(Bp + kt);
    sh8 b1 = *(const sh8*)(Bp + kt + 8);
    sh8 b2 = *(const sh8*)(Bp + kt + 16);
    sh8 b3 = *(const sh8*)(Bp + kt + 24);
    __syncthreads();
    *(sh8*)(AsW) = a0; *(sh8*)(AsW + 8) = a1; *(sh8*)(AsW + 16) = a2; *(sh8*)(AsW + 24) = a3;
    *(sh8*)(BsW) = b0; *(sh8*)(BsW + 8) = b1; *(sh8*)(BsW + 16) = b2; *(sh8*)(BsW + 24) = b3;
    __syncthreads();
    #pragma unroll
    for (int kh = 0; kh < 2; kh++) {
      sh8 af[4], bfv[4];
      const int kofs = kh * 32 + ko;
      #pragma unroll
      for (int mi = 0; mi < 4; mi++)
        af[mi] = *(const sh8*)&As[(wr * 64 + mi * 16 + fr) * LDT + kofs];
      #pragma unroll
      for (int ni = 0; ni < 4; ni++)
        bfv[ni] = *(const sh8*)&Bs[(wc * 64 + ni * 16 + fr) * LDT + kofs];
      #pragma unroll
      for (int mi = 0; mi < 4; mi++)
        #pragma unroll
        for (int ni = 0; ni < 4; ni++)
          acc[mi][ni] = __builtin_amdgcn_mfma_f32_16x16x32_bf16(af[mi], bfv[ni], acc[mi][ni], 0, 0, 0);
    }
  }
  const int rbase = bm0 + wr * 64 + (lane >> 4) * 4;
  const int cbase = bn0 + wc * 64 + fr;
  #pragma unroll
  for (int mi = 0; mi < 4; mi++)
    #pragma unroll
    for (int ni = 0; ni < 4; ni++)
      #pragma unroll
      for (int r = 0; r < 4; r++) {
        const size_t off = (size_t)(rbase + mi * 16 + r) * N + (cbase + ni * 16);
        if constexpr (OUT_BF16) ((u16*)Cout)[off] = f2bf(acc[mi][ni][r]);
        else                    ((float*)Cout)[off] = acc[mi][ni][r];
      }
}

// ---- mean-pool kc/vc -> kpb[bh][128][64] bf16, vpT[bh][64][128] bf16 (pad zeroed) ----
__global__ __launch_bounds__(64)
void k_pool(const u16* __restrict__ proj, u16* __restrict__ kpb, u16* __restrict__ vpT) {
  const int j = blockIdx.x;    // 0..127 (127 = zero pad)
  const int bh = blockIdx.y;   // 0..31
  const int b = bh >> 4, h = bh & 15;
  const int d = threadIdx.x;
  u16 kout = 0, vout = 0;
  if (j < 127) {
    const size_t base = (size_t)(b * 2048 + j * 16) * 5120;
    const size_t kcol = 3072 + h * 64 + d;
    const size_t vcol = 4096 + h * 64 + d;
    float ks = 0.f, vs = 0.f;
    #pragma unroll 4
    for (int r = 0; r < 32; r++) {
      const size_t off = base + (size_t)r * 5120;
      ks += bf2f(proj[off + kcol]);
      vs += bf2f(proj[off + vcol]);
    }
    kout = f2bf(ks * (1.f / 32.f));
    vout = f2bf(vs * (1.f / 32.f));
  }
  kpb[((size_t)bh * 128 + j) * 64 + d] = kout;
  vpT[((size_t)bh * 64 + d) * 128 + j] = vout;
}

// ---- transpose vl: proj cols [2048,3072) -> vlT[bh][64 d][2048 t] bf16 ----
__global__ __launch_bounds__(256)
void k_vt(const u16* __restrict__ proj, u16* __restrict__ vlT) {
  __shared__ u16 tile[64][72];
  const int tt = blockIdx.x;   // 0..31 token tile
  const int bh = blockIdx.y;   // 0..31
  const int b = bh >> 4, h = bh & 15;
  const int t = threadIdx.x;
  const int r = t >> 2;          // 0..63
  const int c0 = (t & 3) * 16;
  const u16* sp = proj + (size_t)(b * 2048 + tt * 64 + r) * 5120 + 2048 + h * 64 + c0;
  us8 v0 = *(const us8*)sp;
  us8 v1 = *(const us8*)(sp + 8);
  #pragma unroll
  for (int jj = 0; jj < 8; jj++) { tile[r][c0 + jj] = v0[jj]; tile[r][c0 + 8 + jj] = v1[jj]; }
  __syncthreads();
  u16* op = vlT + ((size_t)bh * 64 + r) * 2048 + tt * 64 + c0;
  #pragma unroll
  for (int jj = 0; jj < 16; jj++) op[jj] = tile[c0 + jj][r];
}

// ---------------- MFMA attention v3: single barrier, per-wave independent ----------------
// Block = (64-query tile qt, bh). Wave w owns queries [q0+16w, q0+16w+16).
// LDS: KL[192][72] u16 @0 (27648 B, gl_lds-staged, shared, rows j = q0-128+row)
//      Pw[4][16][160] u16 @13824 u16 (20480 B, per-wave private: P then Y)
// Per wave after the one barrier:
//   QK-local (KL, 144-key window) -> softmax -> Pl -> PV-local (vlT global B)
//   QK-comp (kpb global A) -> softmax -> Pc -> PV-comp (vpT global B)
//   Y transpose via own region -> coalesced store.
__global__ __launch_bounds__(256)
void k_attn_mfma(const u16* __restrict__ proj, const u16* __restrict__ kpb,
                 const u16* __restrict__ vpT, const u16* __restrict__ vlT,
                 u16* __restrict__ yb) {
  __shared__ __align__(16) u16 SB[24064];   // 48128 B
  const int qt = blockIdx.x;          // 0..31
  const int bh = blockIdx.y;          // 0..31
  const int b = bh >> 4, h = bh & 15;
  const int tid = threadIdx.x;
  const int wave = tid >> 6;
  const int lane = tid & 63;
  const int fr = lane & 15;
  const int g  = lane >> 4;
  const int ko = g * 8;
  const int q0 = qt * 64;
  const int wq0 = q0 + wave * 16;
  const int i_abs = wq0 + fr;          // this lane's q column

  const u16* prow = proj + (size_t)(b * 2048) * 5120;

  // ---- stage KL: rows j = q0-128+row, row in [0,192), 72-u16 stride ----
  const u16* klb = prow + 1024 + h * 64;
  #pragma unroll
  for (int it = 0; it < 7; it++) {
    const int inst = it * 4 + wave;
    if (inst < 27) {
      const int c = inst * 64 + lane;       // chunk id
      const int row = c / 9;
      const int sl = c - row * 9;
      int jg = q0 - 128 + row; if (jg < 0) jg = 0;    // clamped rows are masked
      gl16(klb + (size_t)jg * 5120 + (sl & 7) * 8, &SB[inst * 512]);
    }
  }
  // q fragments (independent of barrier)
  const sh8 bq0 = *(const sh8*)(prow + (size_t)i_abs * 5120 + h * 64 + ko);
  const sh8 bq1 = *(const sh8*)(prow + (size_t)i_abs * 5120 + h * 64 + 32 + ko);
  __syncthreads();   // drains vmcnt: KL resident. ONLY block-wide barrier.

  u16* Pw = &SB[13824 + wave * 2560];   // [16][160] u16, private to this wave

  // ===== local QK: 9 frags (144-key window, j = wq0-128+kk) =====
  f4 st[9];
  #pragma unroll
  for (int f = 0; f < 9; f++) st[f] = f4{0.f, 0.f, 0.f, 0.f};
  #pragma unroll
  for (int kh = 0; kh < 2; kh++) {
    const sh8 bq = kh ? bq1 : bq0;
    #pragma unroll
    for (int f = 0; f < 9; f++) {
      sh8 ak = *(const sh8*)&SB[(wave * 16 + f * 16 + fr) * 72 + kh * 32 + ko];
      st[f] = __builtin_amdgcn_mfma_f32_16x16x32_bf16(ak, bq, st[f], 0, 0, 0);
    }
  }
  // softmax over k (rows): mask, in-lane + cross-g reduce
  const int klo = 128 - wq0;    // kk >= klo <=> j >= 0
  float m = -1e30f;
  #pragma unroll
  for (int f = 0; f < 9; f++)
    #pragma unroll
    for (int r = 0; r < 4; r++) {
      const int kk = f * 16 + g * 4 + r;
      const bool ok = (kk > fr) && (kk <= fr + 128) && (kk >= klo);
      const float v = ok ? st[f][r] * 0.125f : -1e30f;
      st[f][r] = v; m = fmaxf(m, v);
    }
  m = fmaxf(m, __shfl_xor(m, 16));
  m = fmaxf(m, __shfl_xor(m, 32));
  float l = 0.f;
  #pragma unroll
  for (int f = 0; f < 9; f++)
    #pragma unroll
    for (int r = 0; r < 4; r++) {
      const float p = __expf(st[f][r] - m);
      st[f][r] = p; l += p;
    }
  l += __shfl_xor(l, 16);
  l += __shfl_xor(l, 32);
  {
    const float inv = 1.f / l;      // l>0: key j=i always allowed
    #pragma unroll
    for (int f = 0; f < 9; f++) {
      ui2 pk;
      pk[0] = (u32)f2bf(st[f][0] * inv) | ((u32)f2bf(st[f][1] * inv) << 16);
      pk[1] = (u32)f2bf(st[f][2] * inv) | ((u32)f2bf(st[f][3] * inv) << 16);
      *(ui2*)&Pw[fr * 160 + f * 16 + g * 4] = pk;
    }
    *(ui2*)&Pw[fr * 160 + 144 + g * 4] = ui2{0u, 0u};   // zero pad kk in [144,160)
  }
  // ===== PV-local: 5 slots of 32 keys =====
  f4 yacc[4];
  #pragma unroll
  for (int ni = 0; ni < 4; ni++) yacc[ni] = f4{0.f, 0.f, 0.f, 0.f};
  const u16* vt = vlT + (size_t)bh * 64 * 2048;
  #pragma unroll
  for (int ks = 0; ks < 5; ks++) {
    sh8 pa = *(const sh8*)&Pw[fr * 160 + ks * 32 + ko];
    int jb = wq0 - 128 + ks * 32 + ko;
    if (ks * 32 + ko >= 144) jb = 0;      // fully-padded span (P=0): any valid addr
    if (jb < 0) jb = 0;                   // fully-masked span
    #pragma unroll
    for (int ni = 0; ni < 4; ni++) {
      sh8 vb = *(const sh8*)(vt + (size_t)(ni * 16 + fr) * 2048 + jb);
      yacc[ni] = __builtin_amdgcn_mfma_f32_16x16x32_bf16(pa, vb, yacc[ni], 0, 0, 0);
    }
  }

  // ===== comp QK: nf frags, A direct from global kpb (2KB segments, L2-hot) =====
  const int nf = ((wq0 + 15) >> 8) + 1;   // 1..8, wave-uniform
  f4 sc[8];
  #pragma unroll
  for (int f = 0; f < 8; f++) sc[f] = f4{0.f, 0.f, 0.f, 0.f};
  const u16* kpr = kpb + (size_t)bh * 8192;
  #pragma unroll
  for (int kh = 0; kh < 2; kh++) {
    const sh8 bq = kh ? bq1 : bq0;
    #pragma unroll
    for (int f = 0; f < 8; f++)
      if (f < nf) {
        sh8 ak = *(const sh8*)(kpr + (size_t)(f * 16 + fr) * 64 + kh * 32 + ko);
        sc[f] = __builtin_amdgcn_mfma_f32_16x16x32_bf16(ak, bq, sc[f], 0, 0, 0);
      }
  }
  float m2 = -1e30f;
  #pragma unroll
  for (int f = 0; f < 8; f++)
    #pragma unroll
    for (int r = 0; r < 4; r++) {
      const int jj = f * 16 + g * 4 + r;
      const bool ok = (jj <= 126) && (16 * jj <= i_abs);
      const float v = ok ? sc[f][r] * 0.125f : -1e30f;
      sc[f][r] = v; m2 = fmaxf(m2, v);
    }
  m2 = fmaxf(m2, __shfl_xor(m2, 16));
  m2 = fmaxf(m2, __shfl_xor(m2, 32));
  float l2 = 0.f;
  #pragma unroll
  for (int f = 0; f < 8; f++)
    #pragma unroll
    for (int r = 0; r < 4; r++) {
      const float p = __expf(sc[f][r] - m2);
      sc[f][r] = p; l2 += p;
    }
  l2 += __shfl_xor(l2, 16);
  l2 += __shfl_xor(l2, 32);
  const int nks = (nf + 1) >> 1;
  {
    const float inv2 = 1.f / l2;    // l2>0: block 0 allowed for every i
    #pragma unroll
    for (int f = 0; f < 8; f++)
      if (f < nf) {
        ui2 pk;
        pk[0] = (u32)f2bf(sc[f][0] * inv2) | ((u32)f2bf(sc[f][1] * inv2) << 16);
        pk[1] = (u32)f2bf(sc[f][2] * inv2) | ((u32)f2bf(sc[f][3] * inv2) << 16);
        *(ui2*)&Pw[fr * 160 + f * 16 + g * 4] = pk;
      }
    if (nf & 1)
      *(ui2*)&Pw[fr * 160 + nf * 16 + g * 4] = ui2{0u, 0u};   // pad odd frag to slot
  }
  // ===== PV-comp =====
  const u16* vpt = vpT + (size_t)bh * 8192;
  #pragma unroll
  for (int ks = 0; ks < 4; ks++)
    if (ks < nks) {
      sh8 pa = *(const sh8*)&Pw[fr * 160 + ks * 32 + ko];
      #pragma unroll
      for (int ni = 0; ni < 4; ni++) {
        sh8 vb = *(const sh8*)(vpt + (size_t)(ni * 16 + fr) * 128 + ks * 32 + ko);
        yacc[ni] = __builtin_amdgcn_mfma_f32_16x16x32_bf16(pa, vb, yacc[ni], 0, 0, 0);
      }
    }

  // ===== Y transpose via own region, coalesced store =====
  // lane (g,fr) holds Y[q=4g+r][d=16ni+fr]
  #pragma unroll
  for (int ni = 0; ni < 4; ni++)
    #pragma unroll
    for (int r = 0; r < 4; r++)
      Pw[(4 * g + r) * 72 + ni * 16 + fr] = f2bf(yacc[ni][r]);
  {
    const int row = lane >> 2;          // 0..15
    const int c0 = (lane & 3) * 16;
    u16* gy = yb + (size_t)(b * 2048 + wq0 + row) * 1024 + h * 64 + c0;
    *(us8*)gy       = *(const us8*)&Pw[row * 72 + c0];
    *(us8*)(gy + 8) = *(const us8*)&Pw[row * 72 + c0 + 8];
  }
}

extern "C" void kernel_launch(void* const* d_in, const int* in_sizes, int n_in,
                              void* d_out, int out_size, void* d_ws, size_t ws_size,
                              hipStream_t stream) {
  const float* x  = (const float*)d_in[0];
  const float* Wq = (const float*)d_in[1];
  const float* Wl = (const float*)d_in[2];
  const float* Wc = (const float*)d_in[3];
  const float* Wo = (const float*)d_in[4];
  // dkc/dvc unused: n_def == 0 at T=2048.
  float* out = (float*)d_out;
  char* ws = (char*)d_ws;
  // workspace (72.4 MB): vlT aliases xb (xb dead after gemm1)
  u16* xb   = (u16*)(ws);                       //  8 MB  x bf16 [4096][1024]
  u16* vlT  = (u16*)(ws);                       //  8 MB  vl^T bf16 [32][64][2048] (after gemm1)
  u16* Wt   = (u16*)(ws + 8388608);             // 12 MB  weights^T bf16 [6144][1024]
  u16* proj = (u16*)(ws + 20971520);            // 40 MB  [4096][5120] q|kl|vl|kc|vc
  u16* kpb  = (u16*)(ws + 62914560);            // 512 KB pooled K bf16 [32][128][64]
  u16* vpT  = (u16*)(ws + 63438848);            // 512 KB pooled V^T bf16 [32][64][128]
  u16* yb   = (u16*)(ws + 63963136);            //  8 MB  y bf16 [4096][1024]

  k_cvt_bf16<<<2048, 256, 0, stream>>>(x, xb, 4194304 / 8);
  k_prep_w<<<dim3(96, 16), 256, 0, stream>>>(Wq, Wl, Wc, Wo, Wt);
  k_gemm_bt<true><<<dim3(40, 32), 256, 0, stream>>>(xb, Wt, proj, 4096, 5120, 1024);
  k_pool<<<dim3(128, 32), 64, 0, stream>>>(proj, kpb, vpT);
  k_vt<<<dim3(32, 32), 256, 0, stream>>>(proj, vlT);
  k_attn_mfma<<<dim3(32, 32), 256, 0, stream>>>(proj, kpb, vpT, vlT, yb);
  k_gemm_bt<false><<<dim3(8, 32), 256, 0, stream>>>(yb, Wt + (size_t)5120 * 1024, out, 4096, 1024, 1024);
}

// Round 5
// 153.847 us; speedup vs baseline: 1.1411x; 1.1299x over previous
//
#include <hip/hip_runtime.h>

typedef unsigned short u16;
typedef unsigned int u32;
typedef __attribute__((ext_vector_type(8))) short sh8;           // 8 bf16 (4 VGPR)
typedef __attribute__((ext_vector_type(8))) unsigned short us8;
typedef __attribute__((ext_vector_type(2))) unsigned int ui2;
typedef __attribute__((ext_vector_type(4))) float f4;

__device__ __forceinline__ float bf2f(u16 u) {
  union { unsigned u; float f; } v; v.u = ((unsigned)u) << 16; return v.f;
}
__device__ __forceinline__ u16 f2bf(float f) {
  union { float f; unsigned u; } v; v.f = f;
  unsigned r = v.u + 0x7fffu + ((v.u >> 16) & 1u);   // RNE, inputs finite
  return (u16)(r >> 16);
}
// async global->LDS, 16B per lane; dest = wave-uniform base + lane*16
__device__ __forceinline__ void gl16(const void* g, void* l) {
  __builtin_amdgcn_global_load_lds(
      (const __attribute__((address_space(1))) unsigned int*)g,
      (__attribute__((address_space(3))) unsigned int*)l, 16, 0, 0);
}

// ---------------- f32 -> bf16, 8 elems/thread ----------------
__global__ __launch_bounds__(256)
void k_cvt_bf16(const float* __restrict__ in, u16* __restrict__ out, int n8) {
  int idx = blockIdx.x * 256 + threadIdx.x;
  if (idx >= n8) return;
  const f4* p = (const f4*)in + (size_t)idx * 2;
  f4 a = p[0], b = p[1];
  us8 o;
  o[0] = f2bf(a[0]); o[1] = f2bf(a[1]); o[2] = f2bf(a[2]); o[3] = f2bf(a[3]);
  o[4] = f2bf(b[0]); o[5] = f2bf(b[1]); o[6] = f2bf(b[2]); o[7] = f2bf(b[3]);
  ((us8*)out)[idx] = o;
}

// ------- weights: concat + transpose to Wt[n][k] bf16, n in [0,6144) -------
__global__ __launch_bounds__(256)
void k_prep_w(const float* __restrict__ Wq, const float* __restrict__ Wl,
              const float* __restrict__ Wc, const float* __restrict__ Wo,
              u16* __restrict__ Wt) {
  __shared__ u16 tile[64][65];
  const int n0 = blockIdx.x * 64;
  const int k0 = blockIdx.y * 64;
  const float* src; int ld, col0;
  if (n0 < 1024)      { src = Wq; ld = 1024; col0 = n0; }
  else if (n0 < 3072) { src = Wl; ld = 2048; col0 = n0 - 1024; }
  else if (n0 < 5120) { src = Wc; ld = 2048; col0 = n0 - 3072; }
  else                { src = Wo; ld = 1024; col0 = n0 - 5120; }
  const int t = threadIdx.x;
  const int r = t >> 2;          // 0..63
  const int c0 = (t & 3) * 16;   // 0,16,32,48
  const float* sp = src + (size_t)(k0 + r) * ld + col0 + c0;
  #pragma unroll
  for (int j = 0; j < 16; j++) tile[r][c0 + j] = f2bf(sp[j]);
  __syncthreads();
  u16* op = Wt + (size_t)(n0 + r) * 1024 + k0 + c0;
  #pragma unroll
  for (int j = 0; j < 16; j++) op[j] = tile[c0 + j][r];
}

// ---- bf16 MFMA GEMM (round-2 known-good), A[M][K] * Bt[N][K]^T -> C[M][N] ----
template<bool OUT_BF16>
__global__ __launch_bounds__(256, 2)
void k_gemm_bt(const u16* __restrict__ A, const u16* __restrict__ Bt,
               void* __restrict__ Cout, int M, int N, int K) {
  constexpr int LDT = 72;
  __shared__ __align__(16) u16 As[128 * LDT];
  __shared__ __align__(16) u16 Bs[128 * LDT];
  const int bm0 = blockIdx.y * 128;
  const int bn0 = blockIdx.x * 128;
  const int t = threadIdx.x;
  const int lane = t & 63;
  const int wave = t >> 6;
  const int wr = wave >> 1, wc = wave & 1;
  f4 acc[4][4] = {};
  const int sr = t >> 1;
  const int sc = (t & 1) * 32;
  const u16* Ap = A + (size_t)(bm0 + sr) * K + sc;
  const u16* Bp = Bt + (size_t)(bn0 + sr) * K + sc;
  u16* AsW = &As[sr * LDT + sc];
  u16* BsW = &Bs[sr * LDT + sc];
  const int fr = lane & 15;
  const int ko = (lane >> 4) * 8;
  for (int kt = 0; kt < K; kt += 64) {
    sh8 a0 = *(const sh8*)(Ap + kt);
    sh8 a1 = *(const sh8*)(Ap + kt + 8);
    sh8 a2 = *(const sh8*)(Ap + kt + 16);
    sh8 a3 = *(const sh8*)(Ap + kt + 24);
    sh8 b0 = *(const sh8*)(Bp + kt);
    sh8 b1 = *(const sh8*)(Bp + kt + 8);
    sh8 b2 = *(const sh8*)(Bp + kt + 16);
    sh8 b3 = *(const sh8*)(Bp + kt + 24);
    __syncthreads();
    *(sh8*)(AsW) = a0; *(sh8*)(AsW + 8) = a1; *(sh8*)(AsW + 16) = a2; *(sh8*)(AsW + 24) = a3;
    *(sh8*)(BsW) = b0; *(sh8*)(BsW + 8) = b1; *(sh8*)(BsW + 16) = b2; *(sh8*)(BsW + 24) = b3;
    __syncthreads();
    #pragma unroll
    for (int kh = 0; kh < 2; kh++) {
      sh8 af[4], bfv[4];
      const int kofs = kh * 32 + ko;
      #pragma unroll
      for (int mi = 0; mi < 4; mi++)
        af[mi] = *(const sh8*)&As[(wr * 64 + mi * 16 + fr) * LDT + kofs];
      #pragma unroll
      for (int ni = 0; ni < 4; ni++)
        bfv[ni] = *(const sh8*)&Bs[(wc * 64 + ni * 16 + fr) * LDT + kofs];
      #pragma unroll
      for (int mi = 0; mi < 4; mi++)
        #pragma unroll
        for (int ni = 0; ni < 4; ni++)
          acc[mi][ni] = __builtin_amdgcn_mfma_f32_16x16x32_bf16(af[mi], bfv[ni], acc[mi][ni], 0, 0, 0);
    }
  }
  const int rbase = bm0 + wr * 64 + (lane >> 4) * 4;
  const int cbase = bn0 + wc * 64 + fr;
  #pragma unroll
  for (int mi = 0; mi < 4; mi++)
    #pragma unroll
    for (int ni = 0; ni < 4; ni++)
      #pragma unroll
      for (int r = 0; r < 4; r++) {
        const size_t off = (size_t)(rbase + mi * 16 + r) * N + (cbase + ni * 16);
        if constexpr (OUT_BF16) ((u16*)Cout)[off] = f2bf(acc[mi][ni][r]);
        else                    ((float*)Cout)[off] = acc[mi][ni][r];
      }
}

// ---- mean-pool kc/vc -> kpb[bh][128][64] bf16, vpT[bh][64][128] bf16 (pad zeroed) ----
__global__ __launch_bounds__(64)
void k_pool(const u16* __restrict__ proj, u16* __restrict__ kpb, u16* __restrict__ vpT) {
  const int j = blockIdx.x;    // 0..127 (127 = zero pad)
  const int bh = blockIdx.y;   // 0..31
  const int b = bh >> 4, h = bh & 15;
  const int d = threadIdx.x;
  u16 kout = 0, vout = 0;
  if (j < 127) {
    const size_t base = (size_t)(b * 2048 + j * 16) * 5120;
    const size_t kcol = 3072 + h * 64 + d;
    const size_t vcol = 4096 + h * 64 + d;
    float ks = 0.f, vs = 0.f;
    #pragma unroll 4
    for (int r = 0; r < 32; r++) {
      const size_t off = base + (size_t)r * 5120;
      ks += bf2f(proj[off + kcol]);
      vs += bf2f(proj[off + vcol]);
    }
    kout = f2bf(ks * (1.f / 32.f));
    vout = f2bf(vs * (1.f / 32.f));
  }
  kpb[((size_t)bh * 128 + j) * 64 + d] = kout;
  vpT[((size_t)bh * 64 + d) * 128 + j] = vout;
}

// ---- transpose vl: proj cols [2048,3072) -> vlT[bh][64 d][2048 t] bf16 ----
__global__ __launch_bounds__(256)
void k_vt(const u16* __restrict__ proj, u16* __restrict__ vlT) {
  __shared__ u16 tile[64][72];
  const int tt = blockIdx.x;   // 0..31 token tile
  const int bh = blockIdx.y;   // 0..31
  const int b = bh >> 4, h = bh & 15;
  const int t = threadIdx.x;
  const int r = t >> 2;          // 0..63
  const int c0 = (t & 3) * 16;
  const u16* sp = proj + (size_t)(b * 2048 + tt * 64 + r) * 5120 + 2048 + h * 64 + c0;
  us8 v0 = *(const us8*)sp;
  us8 v1 = *(const us8*)(sp + 8);
  #pragma unroll
  for (int jj = 0; jj < 8; jj++) { tile[r][c0 + jj] = v0[jj]; tile[r][c0 + 8 + jj] = v1[jj]; }
  __syncthreads();
  u16* op = vlT + ((size_t)bh * 64 + r) * 2048 + tt * 64 + c0;
  #pragma unroll
  for (int jj = 0; jj < 16; jj++) op[jj] = tile[c0 + jj][r];
}

// ---------------- MFMA attention v5: burst-staged LDS, 2 barriers ----------------
// Block = (64-query tile qt, bh). Wave w owns queries [q0+16w, q0+16w+16).
// LDS (70,656 B total, u16 indices):
//   KL[192][72] @0       (27,648 B) rows j=q0-128+row        -> freed at barrier 2
//   VL[64][200] @13824   (25,600 B) vlT d-major, t-window [q0-128, q0+63] (+pad)
//   VC[64][136] @26624   (17,408 B) vpT d-major, 128 pooled cols (+pad)
//   P (in freed KL): per-wave [16][168] @ wave*2688, local then comp then Y.
__global__ __launch_bounds__(256)
void k_attn_mfma(const u16* __restrict__ proj, const u16* __restrict__ kpb,
                 const u16* __restrict__ vpT, const u16* __restrict__ vlT,
                 u16* __restrict__ yb) {
  __shared__ __align__(16) u16 SB[35328];
  const int qt = blockIdx.x;          // 0..31
  const int bh = blockIdx.y;          // 0..31
  const int b = bh >> 4, h = bh & 15;
  const int tid = threadIdx.x;
  const int wave = tid >> 6;
  const int lane = tid & 63;
  const int fr = lane & 15;
  const int g  = lane >> 4;
  const int ko = g * 8;
  const int q0 = qt * 64;
  const int wq0 = q0 + wave * 16;
  const int i_abs = wq0 + fr;          // this lane's q column

  const u16* prow = proj + (size_t)(b * 2048) * 5120;
  const u16* klb = prow + 1024 + h * 64;
  const u16* vltb = vlT + (size_t)bh * 64 * 2048;
  const u16* vptb = vpT + (size_t)bh * 8192;

  // ===== burst stage: all independent, one drain =====
  // KL: 192 rows x 9 chunks (8 data + 1 pad) = 1728 chunks = 27 insts
  #pragma unroll
  for (int it = 0; it < 7; it++) {
    const int inst = it * 4 + wave;
    if (inst < 27) {
      const int c = inst * 64 + lane;
      const int row = c / 9;
      const int sl = c - row * 9;
      int jg = q0 - 128 + row; if (jg < 0) jg = 0;    // clamped rows are masked
      gl16(klb + (size_t)jg * 5120 + (sl & 7) * 8, &SB[inst * 512]);
    }
  }
  // VL: 64 rows x 25 chunks (24 data + 1 pad) = 1600 chunks = 25 insts
  #pragma unroll
  for (int it = 0; it < 7; it++) {
    const int inst = it * 4 + wave;
    if (inst < 25) {
      const int c = inst * 64 + lane;
      const int row = c / 25;
      const int sl = c - row * 25;
      int tc = q0 - 128 + (sl < 24 ? sl : 0) * 8; if (tc < 0) tc = 0;
      gl16(vltb + (size_t)row * 2048 + tc, &SB[13824 + inst * 512]);
    }
  }
  // VC: 64 rows x 17 chunks (16 data + 1 pad) = 1088 chunks = 17 insts
  #pragma unroll
  for (int it = 0; it < 5; it++) {
    const int inst = it * 4 + wave;
    if (inst < 17) {
      const int c = inst * 64 + lane;
      const int row = c / 17;
      const int sl = c - row * 17;
      gl16(vptb + (size_t)row * 128 + (sl & 15) * 8, &SB[26624 + inst * 512]);
    }
  }
  // Q fragments (global -> reg, independent)
  const sh8 bq0 = *(const sh8*)(prow + (size_t)i_abs * 5120 + h * 64 + ko);
  const sh8 bq1 = *(const sh8*)(prow + (size_t)i_abs * 5120 + h * 64 + 32 + ko);
  __syncthreads();   // barrier 1: drains vmcnt, all stages resident

  // ===== QK-local: 9 frags from KL (144-key window, j = wq0-128+kk) =====
  f4 st[9];
  #pragma unroll
  for (int f = 0; f < 9; f++) st[f] = f4{0.f, 0.f, 0.f, 0.f};
  #pragma unroll
  for (int kh = 0; kh < 2; kh++) {
    const sh8 bq = kh ? bq1 : bq0;
    #pragma unroll
    for (int f = 0; f < 9; f++) {
      sh8 ak = *(const sh8*)&SB[(wave * 16 + f * 16 + fr) * 72 + kh * 32 + ko];
      st[f] = __builtin_amdgcn_mfma_f32_16x16x32_bf16(ak, bq, st[f], 0, 0, 0);
    }
  }
  // ===== QK-comp: nf frags, A direct from global kpb (L2-hot, pre-barrier-2) =====
  const int nf = ((wq0 + 15) >> 8) + 1;   // 1..8, wave-uniform
  f4 sc[8];
  #pragma unroll
  for (int f = 0; f < 8; f++) sc[f] = f4{0.f, 0.f, 0.f, 0.f};
  const u16* kpr = kpb + (size_t)bh * 8192;
  #pragma unroll
  for (int kh = 0; kh < 2; kh++) {
    const sh8 bq = kh ? bq1 : bq0;
    #pragma unroll
    for (int f = 0; f < 8; f++)
      if (f < nf) {
        sh8 ak = *(const sh8*)(kpr + (size_t)(f * 16 + fr) * 64 + kh * 32 + ko);
        sc[f] = __builtin_amdgcn_mfma_f32_16x16x32_bf16(ak, bq, sc[f], 0, 0, 0);
      }
  }

  // ===== softmax local (q = MFMA column -> 2 shfl_xor reduce) =====
  const int klo = 128 - wq0;    // kk >= klo <=> j >= 0
  float m = -1e30f;
  #pragma unroll
  for (int f = 0; f < 9; f++)
    #pragma unroll
    for (int r = 0; r < 4; r++) {
      const int kk = f * 16 + g * 4 + r;
      const bool ok = (kk > fr) && (kk <= fr + 128) && (kk >= klo);
      const float v = ok ? st[f][r] * 0.125f : -1e30f;
      st[f][r] = v; m = fmaxf(m, v);
    }
  m = fmaxf(m, __shfl_xor(m, 16));
  m = fmaxf(m, __shfl_xor(m, 32));
  float l = 0.f;
  #pragma unroll
  for (int f = 0; f < 9; f++)
    #pragma unroll
    for (int r = 0; r < 4; r++) {
      const float p = __expf(st[f][r] - m);
      st[f][r] = p; l += p;
    }
  l += __shfl_xor(l, 16);
  l += __shfl_xor(l, 32);
  const float inv = 1.f / l;      // l>0: key j=i always allowed

  // ===== softmax comp =====
  float m2 = -1e30f;
  #pragma unroll
  for (int f = 0; f < 8; f++)
    #pragma unroll
    for (int r = 0; r < 4; r++) {
      const int jj = f * 16 + g * 4 + r;
      const bool ok = (jj <= 126) && (16 * jj <= i_abs);
      const float v = ok ? sc[f][r] * 0.125f : -1e30f;
      sc[f][r] = v; m2 = fmaxf(m2, v);
    }
  m2 = fmaxf(m2, __shfl_xor(m2, 16));
  m2 = fmaxf(m2, __shfl_xor(m2, 32));
  float l2 = 0.f;
  #pragma unroll
  for (int f = 0; f < 8; f++)
    #pragma unroll
    for (int r = 0; r < 4; r++) {
      const float p = __expf(sc[f][r] - m2);
      sc[f][r] = p; l2 += p;
    }
  l2 += __shfl_xor(l2, 16);
  l2 += __shfl_xor(l2, 32);
  const float inv2 = 1.f / l2;    // l2>0: block 0 allowed for every i

  __syncthreads();   // barrier 2: KL reads done everywhere; KL region becomes P

  u16* Pw = &SB[wave * 2688];     // [16][168] u16, private to this wave
  // ---- P local ----
  #pragma unroll
  for (int f = 0; f < 9; f++) {
    ui2 pk;
    pk[0] = (u32)f2bf(st[f][0] * inv) | ((u32)f2bf(st[f][1] * inv) << 16);
    pk[1] = (u32)f2bf(st[f][2] * inv) | ((u32)f2bf(st[f][3] * inv) << 16);
    *(ui2*)&Pw[fr * 168 + f * 16 + g * 4] = pk;
  }
  *(ui2*)&Pw[fr * 168 + 144 + g * 4] = ui2{0u, 0u};   // zero pad kk in [144,160)

  // ---- PV-local: 5 slots of 32 keys, B from VL in LDS ----
  f4 yacc[4];
  #pragma unroll
  for (int ni = 0; ni < 4; ni++) yacc[ni] = f4{0.f, 0.f, 0.f, 0.f};
  #pragma unroll
  for (int ks = 0; ks < 5; ks++) {
    sh8 pa = *(const sh8*)&Pw[fr * 168 + ks * 32 + ko];
    const int col = wave * 16 + ks * 32 + ko;          // block-window t offset
    #pragma unroll
    for (int ni = 0; ni < 4; ni++) {
      sh8 vb = *(const sh8*)&SB[13824 + (ni * 16 + fr) * 200 + col];
      yacc[ni] = __builtin_amdgcn_mfma_f32_16x16x32_bf16(pa, vb, yacc[ni], 0, 0, 0);
    }
  }

  // ---- P comp (reuse same per-wave rows; wave-private ordering) ----
  const int nks = (nf + 1) >> 1;
  #pragma unroll
  for (int f = 0; f < 8; f++)
    if (f < nf) {
      ui2 pk;
      pk[0] = (u32)f2bf(sc[f][0] * inv2) | ((u32)f2bf(sc[f][1] * inv2) << 16);
      pk[1] = (u32)f2bf(sc[f][2] * inv2) | ((u32)f2bf(sc[f][3] * inv2) << 16);
      *(ui2*)&Pw[fr * 168 + f * 16 + g * 4] = pk;
    }
  if (nf & 1)
    *(ui2*)&Pw[fr * 168 + nf * 16 + g * 4] = ui2{0u, 0u};   // pad odd frag

  // ---- PV-comp: B from VC in LDS ----
  #pragma unroll
  for (int ks = 0; ks < 4; ks++)
    if (ks < nks) {
      sh8 pa = *(const sh8*)&Pw[fr * 168 + ks * 32 + ko];
      #pragma unroll
      for (int ni = 0; ni < 4; ni++) {
        sh8 vb = *(const sh8*)&SB[26624 + (ni * 16 + fr) * 136 + ks * 32 + ko];
        yacc[ni] = __builtin_amdgcn_mfma_f32_16x16x32_bf16(pa, vb, yacc[ni], 0, 0, 0);
      }
    }

  // ===== Y transpose via own P region, coalesced store =====
  #pragma unroll
  for (int ni = 0; ni < 4; ni++)
    #pragma unroll
    for (int r = 0; r < 4; r++)
      Pw[(4 * g + r) * 72 + ni * 16 + fr] = f2bf(yacc[ni][r]);
  {
    const int row = lane >> 2;          // 0..15
    const int c0 = (lane & 3) * 16;
    u16* gy = yb + (size_t)(b * 2048 + wq0 + row) * 1024 + h * 64 + c0;
    *(us8*)gy       = *(const us8*)&Pw[row * 72 + c0];
    *(us8*)(gy + 8) = *(const us8*)&Pw[row * 72 + c0 + 8];
  }
}

extern "C" void kernel_launch(void* const* d_in, const int* in_sizes, int n_in,
                              void* d_out, int out_size, void* d_ws, size_t ws_size,
                              hipStream_t stream) {
  const float* x  = (const float*)d_in[0];
  const float* Wq = (const float*)d_in[1];
  const float* Wl = (const float*)d_in[2];
  const float* Wc = (const float*)d_in[3];
  const float* Wo = (const float*)d_in[4];
  // dkc/dvc unused: n_def == 0 at T=2048.
  float* out = (float*)d_out;
  char* ws = (char*)d_ws;
  // workspace (72.4 MB): vlT aliases xb (xb dead after gemm1)
  u16* xb   = (u16*)(ws);                       //  8 MB  x bf16 [4096][1024]
  u16* vlT  = (u16*)(ws);                       //  8 MB  vl^T bf16 [32][64][2048] (after gemm1)
  u16* Wt   = (u16*)(ws + 8388608);             // 12 MB  weights^T bf16 [6144][1024]
  u16* proj = (u16*)(ws + 20971520);            // 40 MB  [4096][5120] q|kl|vl|kc|vc
  u16* kpb  = (u16*)(ws + 62914560);            // 512 KB pooled K bf16 [32][128][64]
  u16* vpT  = (u16*)(ws + 63438848);            // 512 KB pooled V^T bf16 [32][64][128]
  u16* yb   = (u16*)(ws + 63963136);            //  8 MB  y bf16 [4096][1024]

  k_cvt_bf16<<<2048, 256, 0, stream>>>(x, xb, 4194304 / 8);
  k_prep_w<<<dim3(96, 16), 256, 0, stream>>>(Wq, Wl, Wc, Wo, Wt);
  k_gemm_bt<true><<<dim3(40, 32), 256, 0, stream>>>(xb, Wt, proj, 4096, 5120, 1024);
  k_pool<<<dim3(128, 32), 64, 0, stream>>>(proj, kpb, vpT);
  k_vt<<<dim3(32, 32), 256, 0, stream>>>(proj, vlT);
  k_attn_mfma<<<dim3(32, 32), 256, 0, stream>>>(proj, kpb, vpT, vlT, yb);
  k_gemm_bt<false><<<dim3(8, 32), 256, 0, stream>>>(yb, Wt + (size_t)5120 * 1024, out, 4096, 1024, 1024);
}